// Round 4
// baseline (4480.708 us; speedup 1.0000x reference)
//
#include <hip/hip_runtime.h>
#include <math.h>

#define B_    32
#define NT    197     // tokens (196 patches + cls)
#define NP    196
#define D_    768
#define NH    12
#define HD_   64
#define MLP_  3072
#define QKVD  2304
#define NCLS  1000

typedef unsigned short u16;
typedef __bf16 bf16x8 __attribute__((ext_vector_type(8)));
typedef float  f32x4  __attribute__((ext_vector_type(4)));
struct alignas(8) u16x4_t { u16 x, y, z, w; };

__device__ __forceinline__ u16 f2bf(float f) {
    unsigned u = __builtin_bit_cast(unsigned, f);
    u = u + 0x7FFFu + ((u >> 16) & 1u);
    return (u16)(u >> 16);
}
__device__ __forceinline__ void gload_lds16(const void* g, void* l) {
    __builtin_amdgcn_global_load_lds((const __attribute__((address_space(1))) unsigned*)g,
                                     (__attribute__((address_space(3))) unsigned*)l, 16, 0, 0);
}
// fast GELU (tanh form): abs err ~1e-3, far below the 0.047 threshold
__device__ __forceinline__ float gelu_f(float x) {
    float u = 0.7978845608f * (x + 0.044715f * x * x * x);
    u = fminf(fmaxf(u, -10.f), 10.f);
    float e = __expf(2.f * u);
    float t = (e - 1.f) * __builtin_amdgcn_rcpf(e + 1.f);
    return 0.5f * x * (1.f + t);
}

// ---------------- patchify: x[B,3,224,224] -> tok bf16 [B*196, 768] ----------
__global__ void patchify_k(const float* __restrict__ x, u16* __restrict__ tok) {
    int bp = blockIdx.x;
    int b = bp / NP, p = bp % NP;
    int ph = p / 14, pw = p % 14;
    const float* xb = x + (size_t)b * 3 * 224 * 224;
    u16* trow = tok + (size_t)bp * D_;
    for (int f = threadIdx.x; f < D_; f += blockDim.x) {
        int c = f >> 8;
        int r = f & 255;
        int i = r >> 4, j = r & 15;
        trow[f] = f2bf(xb[((size_t)c * 224 + (ph * 16 + i)) * 224 + (pw * 16 + j)]);
    }
}

// --------------- assemble h (fp32): cls+pos row0, tokemb+pos rows 1..196 -----
__global__ void assemble_h_k(const float* __restrict__ tokemb, const float* __restrict__ cls,
                             const float* __restrict__ pos, float* __restrict__ h) {
    int bn = blockIdx.x;
    int b = bn / NT, n = bn % NT;
    float* hr = h + (size_t)bn * D_;
    const float* pr = pos + (size_t)n * D_;
    if (n == 0) {
        for (int d = threadIdx.x; d < D_; d += blockDim.x) hr[d] = cls[d] + pr[d];
    } else {
        const float* tr = tokemb + ((size_t)b * NP + (n - 1)) * D_;
        for (int d = threadIdx.x; d < D_; d += blockDim.x) hr[d] = tr[d] + pr[d];
    }
}

// ---------------- fp32 -> bf16 weight conversion -----------------------------
__global__ void cvt1_k(const float* __restrict__ src, u16* __restrict__ dst, int n4) {
    int i = (blockIdx.x * 256 + threadIdx.x) * 4;
    if (i >= n4) return;
    float4 v = *(const float4*)(src + i);
    u16x4_t o; o.x = f2bf(v.x); o.y = f2bf(v.y); o.z = f2bf(v.z); o.w = f2bf(v.w);
    *(u16x4_t*)(dst + i) = o;
}

// fused per-layer weight conversion into wbuf [qkv | proj | mlp1 | mlp2]
__global__ void cvtw_k(const float* __restrict__ qw, const float* __restrict__ pw,
                       const float* __restrict__ m1, const float* __restrict__ m2,
                       u16* __restrict__ dst) {
    const size_t n0 = 1769472, n1 = 2359296, n2 = 4718592, n3 = 7077888;
    size_t e = ((size_t)blockIdx.x * 256 + threadIdx.x) * 4;
    if (e >= n3) return;
    const float* src; size_t off;
    if (e < n0)      { src = qw; off = e; }
    else if (e < n1) { src = pw; off = e - n0; }
    else if (e < n2) { src = m1; off = e - n1; }
    else             { src = m2; off = e - n2; }
    float4 v = *(const float4*)(src + off);
    u16x4_t o; o.x = f2bf(v.x); o.y = f2bf(v.y); o.z = f2bf(v.z); o.w = f2bf(v.w);
    *(u16x4_t*)(dst + e) = o;
}

// ---------------- LayerNorm over last dim (768), fp32 in, fp32/bf16 out ------
template<int OUTBF>
__global__ __launch_bounds__(256) void ln_k(const float* __restrict__ in, size_t in_row_stride,
                                            const float* __restrict__ w, const float* __restrict__ b,
                                            float* __restrict__ of, u16* __restrict__ ob) {
    int row = blockIdx.x;
    const float* xr = in + (size_t)row * in_row_stride;
    int tid = threadIdx.x;
    float s1 = 0.f, s2 = 0.f;
    for (int d = tid; d < D_; d += 256) { float v = xr[d]; s1 += v; s2 += v * v; }
    #pragma unroll
    for (int off = 32; off; off >>= 1) { s1 += __shfl_down(s1, off); s2 += __shfl_down(s2, off); }
    __shared__ float r1[4], r2[4];
    int wave = tid >> 6, lane = tid & 63;
    if (lane == 0) { r1[wave] = s1; r2[wave] = s2; }
    __syncthreads();
    float m1 = (r1[0] + r1[1] + r1[2] + r1[3]) * (1.0f / D_);
    float m2 = (r2[0] + r2[1] + r2[2] + r2[3]) * (1.0f / D_);
    float rs = rsqrtf(m2 - m1 * m1 + 1e-5f);
    for (int d = tid; d < D_; d += 256) {
        float y = (xr[d] - m1) * rs * w[d] + b[d];
        if (OUTBF) ob[(size_t)row * D_ + d] = f2bf(y);
        else       of[(size_t)row * D_ + d] = y;
    }
}

// ---------------- bf16 MFMA GEMM: C[M,N] = A[M,K] @ W[N,K]^T (+bias) ---------
// 128x128 tile, BK=64, 256 thr = 4 waves in 2x2, each wave 4x4 16x16x32 MFMAs.
// LDS XOR-swizzled in 16B chunks (conflict-free reads).
// Counted-vmcnt 2-deep pipeline (T3/T4): steady state never drains vmcnt to 0.
// Round-3: kx0 MFMAs hoisted BEFORE the lgkm barrier (compiler's counted
// lgkmcnt lets them start when kx0's 8 ds_reads land -> they overlap kx1's
// ds_read latency); s_setprio(1) around MFMA clusters (T5; 2 blocks/CU gives
// the wave role diversity the mechanism needs). MFMA accumulation order is
// bitwise identical to round 2.
// EPI: 0 = store fp32, 1 = fp32 += (residual), 2 = GELU -> bf16, 3 = bf16 store
template<int EPI>
__global__ __launch_bounds__(256) void mgemm_k(const u16* __restrict__ A, const u16* __restrict__ W,
                                               const float* __restrict__ bias, float* __restrict__ Cf,
                                               u16* __restrict__ Cb, int M, int N, int K, int nbn) {
    __shared__ u16 As[2][128 * 64];
    __shared__ u16 Ws[2][128 * 64];
    const int tid = threadIdx.x;
    const int lane = tid & 63, wv = tid >> 6;
    const int wr = wv >> 1, wc = wv & 1;
    // bijective XCD-chunked swizzle (m204): hw assigns blockIdx round-robin to
    // 8 XCDs; remap so each XCD owns a contiguous range of work ids.
    const int nwg = gridDim.x;
    const int orig = blockIdx.x;
    const int xcd = orig & 7;
    const int qq = nwg >> 3, rr = nwg & 7;
    const int lin = (xcd < rr ? xcd * (qq + 1) : rr * (qq + 1) + (xcd - rr) * qq) + (orig >> 3);
    const int bm = (lin / nbn) * 128, bn = (lin % nbn) * 128;
    const int rloc = tid >> 3;                     // 0..31 (LDS row within 32-row chunk)
    const int cs8 = ((tid & 7) ^ (rloc & 7)) * 8;  // swizzled src column (elements)
    const int l15 = lane & 15, quad = lane >> 4;
    const int sw = l15 & 7;                        // read-side swizzle key
    f32x4 acc[4][4] = {};

    auto stage = [&](int sel, int k0) {
        #pragma unroll
        for (int q = 0; q < 4; ++q) {
            int gr = bm + q * 32 + rloc;
            if (gr > M - 1) gr = M - 1;                       // clamp edge tile
            gload_lds16(A + (size_t)gr * K + k0 + cs8, (char*)As[sel] + q * 4096 + tid * 16);
        }
        #pragma unroll
        for (int q = 0; q < 4; ++q) {
            int r = q * 32 + rloc;                            // N is always a multiple of 128
            gload_lds16(W + (size_t)(bn + r) * K + k0 + cs8, (char*)Ws[sel] + q * 4096 + tid * 16);
        }
    };

    const int nk = K >> 6;
    stage(0, 0);
    if (nk > 1) stage(1, 64);
    for (int t = 0; t < nk; ++t) {
        // wait own stage(t) (8 oldest loads); stage(t+1)'s 8 stay in flight.
        // per-wave vmcnt + barrier = collective completion of tile t.
        if (t + 1 < nk) __asm__ volatile("s_waitcnt vmcnt(8)\n\ts_barrier" ::: "memory");
        else            __asm__ volatile("s_waitcnt vmcnt(0)\n\ts_barrier" ::: "memory");
        const u16* Asb = As[t & 1];
        const u16* Wsb = Ws[t & 1];
        bf16x8 af[2][4], bfr[2][4];
        #pragma unroll
        for (int kx = 0; kx < 2; ++kx) {
            const int kc = (kx << 2) + quad;                  // 16B chunk index pre-swizzle
            const int co = (kc ^ sw) * 8;                     // swizzled element offset
            #pragma unroll
            for (int i = 0; i < 4; ++i)
                af[kx][i] = *(const bf16x8*)(Asb + (wr * 64 + i * 16 + l15) * 64 + co);
            #pragma unroll
            for (int j = 0; j < 4; ++j)
                bfr[kx][j] = *(const bf16x8*)(Wsb + (wc * 64 + j * 16 + l15) * 64 + co);
        }
        // kx0 MFMAs overlap kx1 ds_read latency (auto counted lgkmcnt)
        __builtin_amdgcn_s_setprio(1);
        #pragma unroll
        for (int i = 0; i < 4; ++i)
            #pragma unroll
            for (int j = 0; j < 4; ++j)
                acc[i][j] = __builtin_amdgcn_mfma_f32_16x16x32_bf16(af[0][i], bfr[0][j], acc[i][j], 0, 0, 0);
        __builtin_amdgcn_s_setprio(0);
        // all my LDS reads done + everyone past -> buf[t&1] is free to refill
        __asm__ volatile("s_waitcnt lgkmcnt(0)\n\ts_barrier" ::: "memory");
        if (t + 2 < nk) stage(t & 1, (t + 2) << 6);
        __builtin_amdgcn_s_setprio(1);
        #pragma unroll
        for (int i = 0; i < 4; ++i)
            #pragma unroll
            for (int j = 0; j < 4; ++j)
                acc[i][j] = __builtin_amdgcn_mfma_f32_16x16x32_bf16(af[1][i], bfr[1][j], acc[i][j], 0, 0, 0);
        __builtin_amdgcn_s_setprio(0);
    }
    #pragma unroll
    for (int i = 0; i < 4; ++i) {
        int rb = bm + wr * 64 + i * 16 + quad * 4;            // C/D: col=lane&15, row=quad*4+reg
        #pragma unroll
        for (int j = 0; j < 4; ++j) {
            int gc = bn + wc * 64 + j * 16 + l15;
            #pragma unroll
            for (int r = 0; r < 4; ++r) {
                int gr = rb + r;
                if (gr >= M) continue;
                float v = acc[i][j][r];
                if (bias) v += bias[gc];
                size_t idx = (size_t)gr * N + gc;
                if (EPI == 0)      Cf[idx] = v;
                else if (EPI == 1) Cf[idx] += v;
                else if (EPI == 3) Cb[idx] = f2bf(v);
                else Cb[idx] = f2bf(gelu_f(v));
            }
        }
    }
}

// ---------------- head: C[32,1000] = A[32,768] @ W[1000,768]^T + bias --------
// Round-3 rewrite: old version issued 396 scalar loads/wave with acc[32]
// starving load-dest registers -> ~full latency serialization (84 us, all
// counters ~0). Now: 1000 blocks (one per col) x 4 waves (8 rows each);
// per lane just 27 float4 loads, acc[8], 16 waves/CU of TLP. fp32 math
// unchanged.
__global__ __launch_bounds__(256) void head_k(const float* __restrict__ A, const float* __restrict__ W,
                                              const float* __restrict__ bias, float* __restrict__ C) {
    const int c = blockIdx.x;                   // 1000 columns
    const int wvq = threadIdx.x >> 6;           // row-group 0..3 (8 rows each)
    const int lane = threadIdx.x & 63;
    const float4* wrow = (const float4*)(W + (size_t)c * D_);   // 192 float4
    float acc[8];
    #pragma unroll
    for (int r = 0; r < 8; ++r) acc[r] = 0.f;
    #pragma unroll
    for (int i = 0; i < 3; ++i) {
        float4 w4 = wrow[lane + 64 * i];
        #pragma unroll
        for (int r = 0; r < 8; ++r) {
            float4 a4 = *(const float4*)(A + (size_t)(wvq * 8 + r) * D_ + (size_t)(lane + 64 * i) * 4);
            acc[r] += a4.x * w4.x + a4.y * w4.y + a4.z * w4.z + a4.w * w4.w;
        }
    }
    #pragma unroll
    for (int r = 0; r < 8; ++r) {
        #pragma unroll
        for (int off = 32; off; off >>= 1) acc[r] += __shfl_xor(acc[r], off);
    }
    if (lane == 0) {
        const float bb = bias[c];
        #pragma unroll
        for (int r = 0; r < 8; ++r) C[(size_t)(wvq * 8 + r) * NCLS + c] = acc[r] + bb;
    }
}

// ---------------- MFMA attention: one block per (b, head, half) --------------
// K [208][72] bf16 LDS, V^T [64][232] bf16 LDS, per-wave P chunk [16][40].
__global__ __launch_bounds__(256) void attn_k(const u16* __restrict__ qkv, u16* __restrict__ o,
                                              const float* __restrict__ alpha, const float* __restrict__ beta,
                                              const float* __restrict__ gamma, int layer, int poly) {
    __shared__ u16 Kb[208 * 72];
    __shared__ u16 Vt[64 * 232];
    __shared__ u16 Pb[4][16 * 40];
    const int tid = threadIdx.x, wv = tid >> 6, lane = tid & 63;
    const int l15 = lane & 15, quad = lane >> 4;
    const int id = blockIdx.x;
    const int half = id & 1, bh = id >> 1;
    const int hh = bh % NH, b = bh / NH;
    const u16* base = qkv + (size_t)b * NT * QKVD;
    for (int idx = tid; idx < 208 * 64; idx += 256) {
        int m = idx >> 6, d = idx & 63;
        Kb[m * 72 + d] = (m < NT) ? base[(size_t)m * QKVD + D_ + hh * 64 + d] : (u16)0;
    }
    for (int idx = tid; idx < 224 * 64; idx += 256) {
        int m = idx >> 6, d = idx & 63;
        Vt[d * 232 + m] = (m < NT) ? base[(size_t)m * QKVD + 2 * D_ + hh * 64 + d] : (u16)0;
    }
    __syncthreads();
    float pa = 0.f, pcb = 0.f, pg = 0.f;
    if (poly) { pa = alpha[layer * NH + hh]; pcb = beta[layer * NH + hh]; pg = gamma[layer * NH + hh]; }

    for (int qt = half + 2 * wv; qt < 13; qt += 8) {
        int qrow = qt * 16 + l15; if (qrow > NT - 1) qrow = NT - 1;
        const u16* qp = base + (size_t)qrow * QKVD + hh * 64;
        bf16x8 aq0 = *(const bf16x8*)(qp + quad * 8);
        bf16x8 aq1 = *(const bf16x8*)(qp + 32 + quad * 8);
        f32x4 S[13];
        #pragma unroll
        for (int f = 0; f < 13; ++f) {
            const u16* kp = Kb + (f * 16 + l15) * 72;
            bf16x8 b0 = *(const bf16x8*)(kp + quad * 8);
            bf16x8 b1 = *(const bf16x8*)(kp + 32 + quad * 8);
            f32x4 c = {};
            c = __builtin_amdgcn_mfma_f32_16x16x32_bf16(aq0, b0, c, 0, 0, 0);
            c = __builtin_amdgcn_mfma_f32_16x16x32_bf16(aq1, b1, c, 0, 0, 0);
            S[f] = c;
        }
        float inv[4];
        if (poly) {
            float s[4] = {0.f, 0.f, 0.f, 0.f};
            #pragma unroll
            for (int f = 0; f < 13; ++f) {
                bool iv = (f == 12) && (l15 >= 5);
                #pragma unroll
                for (int r = 0; r < 4; ++r) {
                    float l = S[f][r] * 0.125f;
                    float p = fmaxf(pa * l * l + pcb * l + pg, 0.f);
                    if (iv) p = 0.f;
                    S[f][r] = p;
                    s[r] += p;
                }
            }
            #pragma unroll
            for (int off = 1; off < 16; off <<= 1)
                #pragma unroll
                for (int r = 0; r < 4; ++r) s[r] += __shfl_xor(s[r], off);
            #pragma unroll
            for (int r = 0; r < 4; ++r) inv[r] = 1.f / (s[r] + 1e-6f);
        } else {
            float mx[4] = {-1e30f, -1e30f, -1e30f, -1e30f};
            #pragma unroll
            for (int f = 0; f < 13; ++f) {
                bool iv = (f == 12) && (l15 >= 5);
                #pragma unroll
                for (int r = 0; r < 4; ++r) {
                    float l = iv ? -1e30f : S[f][r] * 0.125f;
                    S[f][r] = l;
                    mx[r] = fmaxf(mx[r], l);
                }
            }
            #pragma unroll
            for (int off = 1; off < 16; off <<= 1)
                #pragma unroll
                for (int r = 0; r < 4; ++r) mx[r] = fmaxf(mx[r], __shfl_xor(mx[r], off));
            float s[4] = {0.f, 0.f, 0.f, 0.f};
            #pragma unroll
            for (int f = 0; f < 13; ++f)
                #pragma unroll
                for (int r = 0; r < 4; ++r) {
                    float e = __expf(S[f][r] - mx[r]);
                    S[f][r] = e;
                    s[r] += e;
                }
            #pragma unroll
            for (int off = 1; off < 16; off <<= 1)
                #pragma unroll
                for (int r = 0; r < 4; ++r) s[r] += __shfl_xor(s[r], off);
            #pragma unroll
            for (int r = 0; r < 4; ++r) inv[r] = 1.f / s[r];
        }
        #pragma unroll
        for (int f = 0; f < 13; ++f)
            #pragma unroll
            for (int r = 0; r < 4; ++r) S[f][r] *= inv[r];
        f32x4 O[4] = {};
        u16* pb = &Pb[wv][0];
        #pragma unroll
        for (int c = 0; c < 7; ++c) {
            int f0 = 2 * c, f1 = 2 * c + 1;
            __asm__ volatile("s_waitcnt lgkmcnt(0)" ::: "memory");
            #pragma unroll
            for (int r = 0; r < 4; ++r) {
                pb[(quad * 4 + r) * 40 + l15]      = f2bf(S[f0][r]);
                pb[(quad * 4 + r) * 40 + 16 + l15] = (f1 < 13) ? f2bf(S[f1][r]) : (u16)0;
            }
            __asm__ volatile("s_waitcnt lgkmcnt(0)" ::: "memory");
            bf16x8 ap = *(const bf16x8*)(pb + l15 * 40 + quad * 8);
            #pragma unroll
            for (int dt = 0; dt < 4; ++dt) {
                bf16x8 bv = *(const bf16x8*)(Vt + (dt * 16 + l15) * 232 + c * 32 + quad * 8);
                O[dt] = __builtin_amdgcn_mfma_f32_16x16x32_bf16(ap, bv, O[dt], 0, 0, 0);
            }
        }
        #pragma unroll
        for (int dt = 0; dt < 4; ++dt)
            #pragma unroll
            for (int r = 0; r < 4; ++r) {
                int n = qt * 16 + quad * 4 + r;
                if (n < NT)
                    o[((size_t)b * NT + n) * D_ + hh * 64 + dt * 16 + l15] = f2bf(O[dt][r]);
            }
    }
}

// -----------------------------------------------------------------------------
extern "C" void kernel_launch(void* const* d_in, const int* in_sizes, int n_in,
                              void* d_out, int out_size, void* d_ws, size_t ws_size,
                              hipStream_t stream) {
    (void)in_sizes; (void)n_in; (void)out_size; (void)ws_size;
    const float* x        = (const float*)d_in[0];
    const float* patch_w  = (const float*)d_in[1];
    const float* patch_b  = (const float*)d_in[2];
    const float* cls_tok  = (const float*)d_in[3];
    const float* pos      = (const float*)d_in[4];
    const float* ln1_w    = (const float*)d_in[5];
    const float* ln1_b    = (const float*)d_in[6];
    const float* qkv_w    = (const float*)d_in[7];
    const float* proj_w   = (const float*)d_in[8];
    const float* proj_b   = (const float*)d_in[9];
    const float* ln2_w    = (const float*)d_in[10];
    const float* ln2_b    = (const float*)d_in[11];
    const float* mlp_w1   = (const float*)d_in[12];
    const float* mlp_b1   = (const float*)d_in[13];
    const float* mlp_w2   = (const float*)d_in[14];
    const float* mlp_b2   = (const float*)d_in[15];
    const float* alpha    = (const float*)d_in[16];
    const float* beta     = (const float*)d_in[17];
    const float* gamma    = (const float*)d_in[18];
    const float* norm_w   = (const float*)d_in[19];
    const float* norm_b   = (const float*)d_in[20];
    const float* head_w   = (const float*)d_in[21];
    const float* head_b   = (const float*)d_in[22];

    const int MASK[12] = {1,0,1,0,1,0,1,0,1,0,1,0};
    const size_t ROWS = (size_t)B_ * NT;   // 6304

    char* p = (char*)d_ws;
    float* h    = (float*)p;  p += ROWS * D_ * 4;          // 19.4 MB
    float* qkvb = (float*)p;  p += ROWS * QKVD * 4;        // 58.1 MB (tokemb fp32 / qkv bf16)
    u16*   abuf = (u16*)p;    p += ROWS * D_ * 2;          // 9.7 MB  (ln/attn outs)
    u16*   gbuf = (u16*)p;    p += ROWS * MLP_ * 2;        // 38.7 MB (gelu out; also tok)
    u16*   wbuf = (u16*)p;    p += (size_t)7077888 * 2;    // 14.2 MB (per-layer bf16 weights)
    float* hb   = (float*)p;  p += 32 * D_ * 4;
    u16*   qkvbf = (u16*)qkvb;

    u16* wq = wbuf;
    u16* wp = wq + 1769472;
    u16* w1 = wp + 589824;
    u16* w2 = w1 + 2359296;

    // ---- patch embedding (bf16 MFMA) ----
    cvt1_k<<<576, 256, 0, stream>>>(patch_w, wbuf, 589824);
    patchify_k<<<B_ * NP, 256, 0, stream>>>(x, gbuf);
    mgemm_k<0><<<6 * 49, 256, 0, stream>>>(gbuf, wbuf, patch_b, qkvb, nullptr,
                                           B_ * NP, D_, D_, 6);
    assemble_h_k<<<B_ * NT, 256, 0, stream>>>(qkvb, cls_tok, pos, h);

    // ---- transformer layers ----
    for (int i = 0; i < 12; ++i) {
        cvtw_k<<<6912, 256, 0, stream>>>(qkv_w + (size_t)i * 1769472, proj_w + (size_t)i * 589824,
                                         mlp_w1 + (size_t)i * 2359296, mlp_w2 + (size_t)i * 2359296, wbuf);
        ln_k<1><<<(int)ROWS, 256, 0, stream>>>(h, D_, ln1_w + (size_t)i * D_, ln1_b + (size_t)i * D_,
                                               nullptr, abuf);
        mgemm_k<3><<<18 * 50, 256, 0, stream>>>(abuf, wq, nullptr, nullptr, qkvbf,
                                                (int)ROWS, QKVD, D_, 18);
        attn_k<<<B_ * NH * 2, 256, 0, stream>>>(qkvbf, abuf, alpha, beta, gamma, i, MASK[i]);
        mgemm_k<1><<<6 * 50, 256, 0, stream>>>(abuf, wp, proj_b + (size_t)i * D_, h, nullptr,
                                               (int)ROWS, D_, D_, 6);
        ln_k<1><<<(int)ROWS, 256, 0, stream>>>(h, D_, ln2_w + (size_t)i * D_, ln2_b + (size_t)i * D_,
                                               nullptr, abuf);
        mgemm_k<2><<<24 * 50, 256, 0, stream>>>(abuf, w1, mlp_b1 + (size_t)i * MLP_,
                                                nullptr, gbuf, (int)ROWS, MLP_, D_, 24);
        mgemm_k<1><<<6 * 50, 256, 0, stream>>>(gbuf, w2, mlp_b2 + (size_t)i * D_, h, nullptr,
                                               (int)ROWS, D_, MLP_, 6);
    }

    // ---- head: LN(cls rows) fp32, then col-per-block fp32 matvec ------------
    ln_k<0><<<B_, 256, 0, stream>>>(h, (size_t)NT * D_, norm_w, norm_b, hb, nullptr);
    head_k<<<NCLS, 256, 0, stream>>>(hb, head_w, head_b, (float*)d_out);
}

// Round 5
// 4239.687 us; speedup vs baseline: 1.0568x; 1.0568x over previous
//
#include <hip/hip_runtime.h>
#include <math.h>

#define B_    32
#define NT    197     // tokens (196 patches + cls)
#define NP    196
#define D_    768
#define NH    12
#define HD_   64
#define MLP_  3072
#define QKVD  2304
#define NCLS  1000

typedef unsigned short u16;
typedef __bf16 bf16x8 __attribute__((ext_vector_type(8)));
typedef float  f32x4  __attribute__((ext_vector_type(4)));
struct alignas(8) u16x4_t { u16 x, y, z, w; };

__device__ __forceinline__ u16 f2bf(float f) {
    unsigned u = __builtin_bit_cast(unsigned, f);
    u = u + 0x7FFFu + ((u >> 16) & 1u);
    return (u16)(u >> 16);
}
__device__ __forceinline__ void gload_lds16(const void* g, void* l) {
    __builtin_amdgcn_global_load_lds((const __attribute__((address_space(1))) unsigned*)g,
                                     (__attribute__((address_space(3))) unsigned*)l, 16, 0, 0);
}
// fast GELU (tanh form): abs err ~1e-3, far below the 0.047 threshold
__device__ __forceinline__ float gelu_f(float x) {
    float u = 0.7978845608f * (x + 0.044715f * x * x * x);
    u = fminf(fmaxf(u, -10.f), 10.f);
    float e = __expf(2.f * u);
    float t = (e - 1.f) * __builtin_amdgcn_rcpf(e + 1.f);
    return 0.5f * x * (1.f + t);
}

// ---------------- patchify: x[B,3,224,224] -> tok bf16 [B*196, 768] ----------
__global__ void patchify_k(const float* __restrict__ x, u16* __restrict__ tok) {
    int bp = blockIdx.x;
    int b = bp / NP, p = bp % NP;
    int ph = p / 14, pw = p % 14;
    const float* xb = x + (size_t)b * 3 * 224 * 224;
    u16* trow = tok + (size_t)bp * D_;
    for (int f = threadIdx.x; f < D_; f += blockDim.x) {
        int c = f >> 8;
        int r = f & 255;
        int i = r >> 4, j = r & 15;
        trow[f] = f2bf(xb[((size_t)c * 224 + (ph * 16 + i)) * 224 + (pw * 16 + j)]);
    }
}

// --------------- assemble h (fp32): cls+pos row0, tokemb+pos rows 1..196 -----
__global__ void assemble_h_k(const float* __restrict__ tokemb, const float* __restrict__ cls,
                             const float* __restrict__ pos, float* __restrict__ h) {
    int bn = blockIdx.x;
    int b = bn / NT, n = bn % NT;
    float* hr = h + (size_t)bn * D_;
    const float* pr = pos + (size_t)n * D_;
    if (n == 0) {
        for (int d = threadIdx.x; d < D_; d += blockDim.x) hr[d] = cls[d] + pr[d];
    } else {
        const float* tr = tokemb + ((size_t)b * NP + (n - 1)) * D_;
        for (int d = threadIdx.x; d < D_; d += blockDim.x) hr[d] = tr[d] + pr[d];
    }
}

// ---------------- fp32 -> bf16 weight conversion -----------------------------
__global__ void cvt1_k(const float* __restrict__ src, u16* __restrict__ dst, int n4) {
    int i = (blockIdx.x * 256 + threadIdx.x) * 4;
    if (i >= n4) return;
    float4 v = *(const float4*)(src + i);
    u16x4_t o; o.x = f2bf(v.x); o.y = f2bf(v.y); o.z = f2bf(v.z); o.w = f2bf(v.w);
    *(u16x4_t*)(dst + i) = o;
}

// fused per-layer weight conversion into wbuf [qkv | proj | mlp1 | mlp2]
__global__ void cvtw_k(const float* __restrict__ qw, const float* __restrict__ pw,
                       const float* __restrict__ m1, const float* __restrict__ m2,
                       u16* __restrict__ dst) {
    const size_t n0 = 1769472, n1 = 2359296, n2 = 4718592, n3 = 7077888;
    size_t e = ((size_t)blockIdx.x * 256 + threadIdx.x) * 4;
    if (e >= n3) return;
    const float* src; size_t off;
    if (e < n0)      { src = qw; off = e; }
    else if (e < n1) { src = pw; off = e - n0; }
    else if (e < n2) { src = m1; off = e - n1; }
    else             { src = m2; off = e - n2; }
    float4 v = *(const float4*)(src + off);
    u16x4_t o; o.x = f2bf(v.x); o.y = f2bf(v.y); o.z = f2bf(v.z); o.w = f2bf(v.w);
    *(u16x4_t*)(dst + e) = o;
}

// ---------------- LayerNorm over last dim (768), fp32 in, fp32/bf16 out ------
// Round-4: vectorized. Thread t<192 owns one contiguous float4 (768=192x4);
// wave shfl reduce + 4-slot LDS combine; float4 / u16x4 stores.
template<int OUTBF>
__global__ __launch_bounds__(256) void ln_k(const float* __restrict__ in, size_t in_row_stride,
                                            const float* __restrict__ w, const float* __restrict__ b,
                                            float* __restrict__ of, u16* __restrict__ ob) {
    int row = blockIdx.x;
    const float* xr = in + (size_t)row * in_row_stride;
    int tid = threadIdx.x;
    float4 v = make_float4(0.f, 0.f, 0.f, 0.f);
    if (tid < 192) v = *(const float4*)(xr + (size_t)tid * 4);
    float s1 = v.x + v.y + v.z + v.w;
    float s2 = v.x * v.x + v.y * v.y + v.z * v.z + v.w * v.w;
    #pragma unroll
    for (int off = 32; off; off >>= 1) { s1 += __shfl_down(s1, off); s2 += __shfl_down(s2, off); }
    __shared__ float r1[4], r2[4];
    int wave = tid >> 6, lane = tid & 63;
    if (lane == 0) { r1[wave] = s1; r2[wave] = s2; }
    __syncthreads();
    float m1 = (r1[0] + r1[1] + r1[2] + r1[3]) * (1.0f / D_);
    float m2 = (r2[0] + r2[1] + r2[2] + r2[3]) * (1.0f / D_);
    float rs = rsqrtf(m2 - m1 * m1 + 1e-5f);
    if (tid < 192) {
        float4 wv = *(const float4*)(w + (size_t)tid * 4);
        float4 bv = *(const float4*)(b + (size_t)tid * 4);
        float y0 = (v.x - m1) * rs * wv.x + bv.x;
        float y1 = (v.y - m1) * rs * wv.y + bv.y;
        float y2 = (v.z - m1) * rs * wv.z + bv.z;
        float y3 = (v.w - m1) * rs * wv.w + bv.w;
        if (OUTBF) {
            u16x4_t o; o.x = f2bf(y0); o.y = f2bf(y1); o.z = f2bf(y2); o.w = f2bf(y3);
            *(u16x4_t*)(ob + (size_t)row * D_ + (size_t)tid * 4) = o;
        } else {
            *(float4*)(of + (size_t)row * D_ + (size_t)tid * 4) = make_float4(y0, y1, y2, y3);
        }
    }
}

// ---------------- bf16 MFMA GEMM: C[M,N] = A[M,K] @ W[N,K]^T (+bias) ---------
// 128x128 tile, BK=64, 256 thr = 4 waves in 2x2, each wave 4x4 16x16x32 MFMAs.
// LDS XOR-swizzled in 16B chunks (conflict-free reads).
// Counted-vmcnt 2-deep pipeline (T3/T4). Steady state never drains vmcnt to 0:
// per K-step we wait vmcnt(8) (own stage(t) done, stage(t+1)'s 8 loads stay in
// flight), barrier, ds_read ALL fragments to regs, lgkmcnt(0) + barrier
// (buffer free), issue stage(t+2), then MFMA from regs.
// ROUND-4 NOTE: the round-3 "kx0 MFMA hoist + setprio" variant REGRESSED
// (mlp1 87->110 us, VGPR 88->112): hoisting MFMAs before the lgkm barrier
// delays the buffer-free signal (stage(t+2) issues late every step) and
// setprio in a barrier-locked lockstep block matches m190's negative regime.
// This is the verified round-2 structure — do not re-hoist without A/B.
// EPI: 0 = store fp32, 1 = fp32 += (residual), 2 = GELU -> bf16, 3 = bf16 store
template<int EPI>
__global__ __launch_bounds__(256) void mgemm_k(const u16* __restrict__ A, const u16* __restrict__ W,
                                               const float* __restrict__ bias, float* __restrict__ Cf,
                                               u16* __restrict__ Cb, int M, int N, int K, int nbn) {
    __shared__ u16 As[2][128 * 64];
    __shared__ u16 Ws[2][128 * 64];
    const int tid = threadIdx.x;
    const int lane = tid & 63, wv = tid >> 6;
    const int wr = wv >> 1, wc = wv & 1;
    // bijective XCD-chunked swizzle (m204): hw assigns blockIdx round-robin to
    // 8 XCDs; remap so each XCD owns a contiguous range of work ids.
    const int nwg = gridDim.x;
    const int orig = blockIdx.x;
    const int xcd = orig & 7;
    const int qq = nwg >> 3, rr = nwg & 7;
    const int lin = (xcd < rr ? xcd * (qq + 1) : rr * (qq + 1) + (xcd - rr) * qq) + (orig >> 3);
    const int bm = (lin / nbn) * 128, bn = (lin % nbn) * 128;
    const int rloc = tid >> 3;                     // 0..31 (LDS row within 32-row chunk)
    const int cs8 = ((tid & 7) ^ (rloc & 7)) * 8;  // swizzled src column (elements)
    const int l15 = lane & 15, quad = lane >> 4;
    const int sw = l15 & 7;                        // read-side swizzle key
    f32x4 acc[4][4] = {};

    auto stage = [&](int sel, int k0) {
        #pragma unroll
        for (int q = 0; q < 4; ++q) {
            int gr = bm + q * 32 + rloc;
            if (gr > M - 1) gr = M - 1;                       // clamp edge tile
            gload_lds16(A + (size_t)gr * K + k0 + cs8, (char*)As[sel] + q * 4096 + tid * 16);
        }
        #pragma unroll
        for (int q = 0; q < 4; ++q) {
            int r = q * 32 + rloc;                            // N is always a multiple of 128
            gload_lds16(W + (size_t)(bn + r) * K + k0 + cs8, (char*)Ws[sel] + q * 4096 + tid * 16);
        }
    };

    const int nk = K >> 6;
    stage(0, 0);
    if (nk > 1) stage(1, 64);
    for (int t = 0; t < nk; ++t) {
        // wait own stage(t) (8 oldest loads); stage(t+1)'s 8 stay in flight
        if (t + 1 < nk) __asm__ volatile("s_waitcnt vmcnt(8)\n\ts_barrier" ::: "memory");
        else            __asm__ volatile("s_waitcnt vmcnt(0)\n\ts_barrier" ::: "memory");
        const u16* Asb = As[t & 1];
        const u16* Wsb = Ws[t & 1];
        bf16x8 af[2][4], bfr[2][4];
        #pragma unroll
        for (int kx = 0; kx < 2; ++kx) {
            const int kc = (kx << 2) + quad;                  // 16B chunk index pre-swizzle
            const int co = (kc ^ sw) * 8;                     // swizzled element offset
            #pragma unroll
            for (int i = 0; i < 4; ++i)
                af[kx][i] = *(const bf16x8*)(Asb + (wr * 64 + i * 16 + l15) * 64 + co);
            #pragma unroll
            for (int j = 0; j < 4; ++j)
                bfr[kx][j] = *(const bf16x8*)(Wsb + (wc * 64 + j * 16 + l15) * 64 + co);
        }
        // all my LDS reads done + everyone past -> buf[t&1] is free to refill
        __asm__ volatile("s_waitcnt lgkmcnt(0)\n\ts_barrier" ::: "memory");
        if (t + 2 < nk) stage(t & 1, (t + 2) << 6);
        #pragma unroll
        for (int kx = 0; kx < 2; ++kx)
            #pragma unroll
            for (int i = 0; i < 4; ++i)
                #pragma unroll
                for (int j = 0; j < 4; ++j)
                    acc[i][j] = __builtin_amdgcn_mfma_f32_16x16x32_bf16(af[kx][i], bfr[kx][j], acc[i][j], 0, 0, 0);
    }
    #pragma unroll
    for (int i = 0; i < 4; ++i) {
        int rb = bm + wr * 64 + i * 16 + quad * 4;            // C/D: col=lane&15, row=quad*4+reg
        #pragma unroll
        for (int j = 0; j < 4; ++j) {
            int gc = bn + wc * 64 + j * 16 + l15;
            #pragma unroll
            for (int r = 0; r < 4; ++r) {
                int gr = rb + r;
                if (gr >= M) continue;
                float v = acc[i][j][r];
                if (bias) v += bias[gc];
                size_t idx = (size_t)gr * N + gc;
                if (EPI == 0)      Cf[idx] = v;
                else if (EPI == 1) Cf[idx] += v;
                else if (EPI == 3) Cb[idx] = f2bf(v);
                else Cb[idx] = f2bf(gelu_f(v));
            }
        }
    }
}

// ---------------- head: C[32,1000] = A[32,768] @ W[1000,768]^T + bias --------
// 1000 blocks (one per col) x 4 waves (8 rows each); per lane 27 float4 loads,
// acc[8], 16 waves/CU of TLP. fp32 math identical to reference GEMM.
__global__ __launch_bounds__(256) void head_k(const float* __restrict__ A, const float* __restrict__ W,
                                              const float* __restrict__ bias, float* __restrict__ C) {
    const int c = blockIdx.x;                   // 1000 columns
    const int wvq = threadIdx.x >> 6;           // row-group 0..3 (8 rows each)
    const int lane = threadIdx.x & 63;
    const float4* wrow = (const float4*)(W + (size_t)c * D_);   // 192 float4
    float acc[8];
    #pragma unroll
    for (int r = 0; r < 8; ++r) acc[r] = 0.f;
    #pragma unroll
    for (int i = 0; i < 3; ++i) {
        float4 w4 = wrow[lane + 64 * i];
        #pragma unroll
        for (int r = 0; r < 8; ++r) {
            float4 a4 = *(const float4*)(A + (size_t)(wvq * 8 + r) * D_ + (size_t)(lane + 64 * i) * 4);
            acc[r] += a4.x * w4.x + a4.y * w4.y + a4.z * w4.z + a4.w * w4.w;
        }
    }
    #pragma unroll
    for (int r = 0; r < 8; ++r) {
        #pragma unroll
        for (int off = 32; off; off >>= 1) acc[r] += __shfl_xor(acc[r], off);
    }
    if (lane == 0) {
        const float bb = bias[c];
        #pragma unroll
        for (int r = 0; r < 8; ++r) C[(size_t)(wvq * 8 + r) * NCLS + c] = acc[r] + bb;
    }
}

// ---------------- MFMA attention: one block per (b, head, half) --------------
// K [208][72] bf16 LDS, V^T [64][232] bf16 LDS, per-wave P chunk [16][40].
__global__ __launch_bounds__(256) void attn_k(const u16* __restrict__ qkv, u16* __restrict__ o,
                                              const float* __restrict__ alpha, const float* __restrict__ beta,
                                              const float* __restrict__ gamma, int layer, int poly) {
    __shared__ u16 Kb[208 * 72];
    __shared__ u16 Vt[64 * 232];
    __shared__ u16 Pb[4][16 * 40];
    const int tid = threadIdx.x, wv = tid >> 6, lane = tid & 63;
    const int l15 = lane & 15, quad = lane >> 4;
    const int id = blockIdx.x;
    const int half = id & 1, bh = id >> 1;
    const int hh = bh % NH, b = bh / NH;
    const u16* base = qkv + (size_t)b * NT * QKVD;
    for (int idx = tid; idx < 208 * 64; idx += 256) {
        int m = idx >> 6, d = idx & 63;
        Kb[m * 72 + d] = (m < NT) ? base[(size_t)m * QKVD + D_ + hh * 64 + d] : (u16)0;
    }
    for (int idx = tid; idx < 224 * 64; idx += 256) {
        int m = idx >> 6, d = idx & 63;
        Vt[d * 232 + m] = (m < NT) ? base[(size_t)m * QKVD + 2 * D_ + hh * 64 + d] : (u16)0;
    }
    __syncthreads();
    float pa = 0.f, pcb = 0.f, pg = 0.f;
    if (poly) { pa = alpha[layer * NH + hh]; pcb = beta[layer * NH + hh]; pg = gamma[layer * NH + hh]; }

    for (int qt = half + 2 * wv; qt < 13; qt += 8) {
        int qrow = qt * 16 + l15; if (qrow > NT - 1) qrow = NT - 1;
        const u16* qp = base + (size_t)qrow * QKVD + hh * 64;
        bf16x8 aq0 = *(const bf16x8*)(qp + quad * 8);
        bf16x8 aq1 = *(const bf16x8*)(qp + 32 + quad * 8);
        f32x4 S[13];
        #pragma unroll
        for (int f = 0; f < 13; ++f) {
            const u16* kp = Kb + (f * 16 + l15) * 72;
            bf16x8 b0 = *(const bf16x8*)(kp + quad * 8);
            bf16x8 b1 = *(const bf16x8*)(kp + 32 + quad * 8);
            f32x4 c = {};
            c = __builtin_amdgcn_mfma_f32_16x16x32_bf16(aq0, b0, c, 0, 0, 0);
            c = __builtin_amdgcn_mfma_f32_16x16x32_bf16(aq1, b1, c, 0, 0, 0);
            S[f] = c;
        }
        float inv[4];
        if (poly) {
            float s[4] = {0.f, 0.f, 0.f, 0.f};
            #pragma unroll
            for (int f = 0; f < 13; ++f) {
                bool iv = (f == 12) && (l15 >= 5);
                #pragma unroll
                for (int r = 0; r < 4; ++r) {
                    float l = S[f][r] * 0.125f;
                    float p = fmaxf(pa * l * l + pcb * l + pg, 0.f);
                    if (iv) p = 0.f;
                    S[f][r] = p;
                    s[r] += p;
                }
            }
            #pragma unroll
            for (int off = 1; off < 16; off <<= 1)
                #pragma unroll
                for (int r = 0; r < 4; ++r) s[r] += __shfl_xor(s[r], off);
            #pragma unroll
            for (int r = 0; r < 4; ++r) inv[r] = 1.f / (s[r] + 1e-6f);
        } else {
            float mx[4] = {-1e30f, -1e30f, -1e30f, -1e30f};
            #pragma unroll
            for (int f = 0; f < 13; ++f) {
                bool iv = (f == 12) && (l15 >= 5);
                #pragma unroll
                for (int r = 0; r < 4; ++r) {
                    float l = iv ? -1e30f : S[f][r] * 0.125f;
                    S[f][r] = l;
                    mx[r] = fmaxf(mx[r], l);
                }
            }
            #pragma unroll
            for (int off = 1; off < 16; off <<= 1)
                #pragma unroll
                for (int r = 0; r < 4; ++r) mx[r] = fmaxf(mx[r], __shfl_xor(mx[r], off));
            float s[4] = {0.f, 0.f, 0.f, 0.f};
            #pragma unroll
            for (int f = 0; f < 13; ++f)
                #pragma unroll
                for (int r = 0; r < 4; ++r) {
                    float e = __expf(S[f][r] - mx[r]);
                    S[f][r] = e;
                    s[r] += e;
                }
            #pragma unroll
            for (int off = 1; off < 16; off <<= 1)
                #pragma unroll
                for (int r = 0; r < 4; ++r) s[r] += __shfl_xor(s[r], off);
            #pragma unroll
            for (int r = 0; r < 4; ++r) inv[r] = 1.f / s[r];
        }
        #pragma unroll
        for (int f = 0; f < 13; ++f)
            #pragma unroll
            for (int r = 0; r < 4; ++r) S[f][r] *= inv[r];
        f32x4 O[4] = {};
        u16* pb = &Pb[wv][0];
        #pragma unroll
        for (int c = 0; c < 7; ++c) {
            int f0 = 2 * c, f1 = 2 * c + 1;
            __asm__ volatile("s_waitcnt lgkmcnt(0)" ::: "memory");
            #pragma unroll
            for (int r = 0; r < 4; ++r) {
                pb[(quad * 4 + r) * 40 + l15]      = f2bf(S[f0][r]);
                pb[(quad * 4 + r) * 40 + 16 + l15] = (f1 < 13) ? f2bf(S[f1][r]) : (u16)0;
            }
            __asm__ volatile("s_waitcnt lgkmcnt(0)" ::: "memory");
            bf16x8 ap = *(const bf16x8*)(pb + l15 * 40 + quad * 8);
            #pragma unroll
            for (int dt = 0; dt < 4; ++dt) {
                bf16x8 bv = *(const bf16x8*)(Vt + (dt * 16 + l15) * 232 + c * 32 + quad * 8);
                O[dt] = __builtin_amdgcn_mfma_f32_16x16x32_bf16(ap, bv, O[dt], 0, 0, 0);
            }
        }
        #pragma unroll
        for (int dt = 0; dt < 4; ++dt)
            #pragma unroll
            for (int r = 0; r < 4; ++r) {
                int n = qt * 16 + quad * 4 + r;
                if (n < NT)
                    o[((size_t)b * NT + n) * D_ + hh * 64 + dt * 16 + l15] = f2bf(O[dt][r]);
            }
    }
}

// -----------------------------------------------------------------------------
extern "C" void kernel_launch(void* const* d_in, const int* in_sizes, int n_in,
                              void* d_out, int out_size, void* d_ws, size_t ws_size,
                              hipStream_t stream) {
    (void)in_sizes; (void)n_in; (void)out_size; (void)ws_size;
    const float* x        = (const float*)d_in[0];
    const float* patch_w  = (const float*)d_in[1];
    const float* patch_b  = (const float*)d_in[2];
    const float* cls_tok  = (const float*)d_in[3];
    const float* pos      = (const float*)d_in[4];
    const float* ln1_w    = (const float*)d_in[5];
    const float* ln1_b    = (const float*)d_in[6];
    const float* qkv_w    = (const float*)d_in[7];
    const float* proj_w   = (const float*)d_in[8];
    const float* proj_b   = (const float*)d_in[9];
    const float* ln2_w    = (const float*)d_in[10];
    const float* ln2_b    = (const float*)d_in[11];
    const float* mlp_w1   = (const float*)d_in[12];
    const float* mlp_b1   = (const float*)d_in[13];
    const float* mlp_w2   = (const float*)d_in[14];
    const float* mlp_b2   = (const float*)d_in[15];
    const float* alpha    = (const float*)d_in[16];
    const float* beta     = (const float*)d_in[17];
    const float* gamma    = (const float*)d_in[18];
    const float* norm_w   = (const float*)d_in[19];
    const float* norm_b   = (const float*)d_in[20];
    const float* head_w   = (const float*)d_in[21];
    const float* head_b   = (const float*)d_in[22];

    const int MASK[12] = {1,0,1,0,1,0,1,0,1,0,1,0};
    const size_t ROWS = (size_t)B_ * NT;   // 6304

    char* p = (char*)d_ws;
    float* h    = (float*)p;  p += ROWS * D_ * 4;          // 19.4 MB
    float* qkvb = (float*)p;  p += ROWS * QKVD * 4;        // 58.1 MB (tokemb fp32 / qkv bf16)
    u16*   abuf = (u16*)p;    p += ROWS * D_ * 2;          // 9.7 MB  (ln/attn outs)
    u16*   gbuf = (u16*)p;    p += ROWS * MLP_ * 2;        // 38.7 MB (gelu out; also tok)
    u16*   wbuf = (u16*)p;    p += (size_t)7077888 * 2;    // 14.2 MB (per-layer bf16 weights)
    float* hb   = (float*)p;  p += 32 * D_ * 4;
    u16*   qkvbf = (u16*)qkvb;

    u16* wq = wbuf;
    u16* wp = wq + 1769472;
    u16* w1 = wp + 589824;
    u16* w2 = w1 + 2359296;

    // ---- patch embedding (bf16 MFMA) ----
    cvt1_k<<<576, 256, 0, stream>>>(patch_w, wbuf, 589824);
    patchify_k<<<B_ * NP, 256, 0, stream>>>(x, gbuf);
    mgemm_k<0><<<6 * 49, 256, 0, stream>>>(gbuf, wbuf, patch_b, qkvb, nullptr,
                                           B_ * NP, D_, D_, 6);
    assemble_h_k<<<B_ * NT, 256, 0, stream>>>(qkvb, cls_tok, pos, h);

    // ---- transformer layers ----
    for (int i = 0; i < 12; ++i) {
        cvtw_k<<<6912, 256, 0, stream>>>(qkv_w + (size_t)i * 1769472, proj_w + (size_t)i * 589824,
                                         mlp_w1 + (size_t)i * 2359296, mlp_w2 + (size_t)i * 2359296, wbuf);
        ln_k<1><<<(int)ROWS, 256, 0, stream>>>(h, D_, ln1_w + (size_t)i * D_, ln1_b + (size_t)i * D_,
                                               nullptr, abuf);
        mgemm_k<3><<<18 * 50, 256, 0, stream>>>(abuf, wq, nullptr, nullptr, qkvbf,
                                                (int)ROWS, QKVD, D_, 18);
        attn_k<<<B_ * NH * 2, 256, 0, stream>>>(qkvbf, abuf, alpha, beta, gamma, i, MASK[i]);
        mgemm_k<1><<<6 * 50, 256, 0, stream>>>(abuf, wp, proj_b + (size_t)i * D_, h, nullptr,
                                               (int)ROWS, D_, D_, 6);
        ln_k<1><<<(int)ROWS, 256, 0, stream>>>(h, D_, ln2_w + (size_t)i * D_, ln2_b + (size_t)i * D_,
                                               nullptr, abuf);
        mgemm_k<2><<<24 * 50, 256, 0, stream>>>(abuf, w1, mlp_b1 + (size_t)i * MLP_,
                                                nullptr, gbuf, (int)ROWS, MLP_, D_, 24);
        mgemm_k<1><<<6 * 50, 256, 0, stream>>>(gbuf, w2, mlp_b2 + (size_t)i * D_, h, nullptr,
                                               (int)ROWS, D_, MLP_, 6);
    }

    // ---- head: LN(cls rows) fp32, then col-per-block fp32 matvec ------------
    ln_k<0><<<B_, 256, 0, stream>>>(h, (size_t)NT * D_, norm_w, norm_b, hb, nullptr);
    head_k<<<NCLS, 256, 0, stream>>>(hb, head_w, head_b, (float*)d_out);
}